// Round 1
// baseline (834.527 us; speedup 1.0000x reference)
//
#include <hip/hip_runtime.h>
#include <hip/hip_bf16.h>
#include <stdint.h>

// Problem dims (fixed by the reference setup_inputs):
//   a_previous [8192, 4096] f32, theta [4096, 4098] f32, aging [4096, 4098] f32
//   out [8192, 4096] f32
#define M_DIM 8192
#define N_DIM 4096
#define K_IN  4096          // n_in
#define NC    (K_IN + 2)    // 4098 theta/aging columns
#define K_DIM (2 * K_IN)    // GEMM K: [a | inv(a)] concatenated

#define BM 128
#define BN 128
#define BK 64

typedef __attribute__((ext_vector_type(8))) short short8_t;   // 8 bf16 (4 VGPRs)
typedef __attribute__((ext_vector_type(4))) float f32x4;      // MFMA acc

// round-to-nearest-even f32 -> bf16 (no NaN inputs here)
__device__ __forceinline__ unsigned short f2bf(float f) {
  union { float f; unsigned u; } v; v.f = f;
  unsigned u = v.u;
  return (unsigned short)((u + 0x7FFFu + ((u >> 16) & 1u)) >> 16);
}

// tanh(y) = 1 - 2/(1+e^{2y})
__device__ __forceinline__ float fast_tanh(float y) {
  float e = __expf(2.0f * y);
  return 1.0f - 2.0f * __builtin_amdgcn_rcpf(1.0f + e);
}

// ---------------------------------------------------------------------------
// prep_A: A' = [bf16(a) | bf16(inv(a))], shape [8192][8192] bf16
// one float4 of a per thread; memory-bound (~260 MB traffic)
// ---------------------------------------------------------------------------
__global__ __launch_bounds__(256) void prep_A(const float* __restrict__ a,
                                              unsigned short* __restrict__ Ap) {
  int idx = blockIdx.x * 256 + threadIdx.x;       // 8192*1024 float4s, exact grid
  int j  = idx >> 10;                             // row (1024 float4 per row)
  int k4 = (idx & 1023) << 2;                     // starting col
  float4 v = reinterpret_cast<const float4*>(a)[idx];
  float xs[4] = {v.x, v.y, v.z, v.w};
  ushort4 lv, rv;
  unsigned short l[4], r[4];
#pragma unroll
  for (int t = 0; t < 4; ++t) {
    float x = xs[t];
    l[t] = f2bf(x);
    float tnh = fast_tanh((x + 0.056f) * 3.858f);
    r[t] = f2bf(0.104f - 0.899f * tnh);
  }
  lv.x = l[0]; lv.y = l[1]; lv.z = l[2]; lv.w = l[3];
  rv.x = r[0]; rv.y = r[1]; rv.z = r[2]; rv.w = r[3];
  size_t base = (size_t)j * K_DIM + k4;
  *reinterpret_cast<ushort4*>(Ap + base)        = lv;   // left half: a
  *reinterpret_cast<ushort4*>(Ap + base + K_IN) = rv;   // right half: inv(a)
}

// ---------------------------------------------------------------------------
// prep_B: per row i: th = st(theta*aging); W = |th|/rowsum;
//   B'[i] = [bf16(Wp[:4096]) | bf16(Wn[:4096])]; corr[i] = const-column part (f32)
// one block per row; th staged in LDS to avoid a second global read
// ---------------------------------------------------------------------------
__global__ __launch_bounds__(256) void prep_B(const float* __restrict__ theta,
                                              const float* __restrict__ aging,
                                              unsigned short* __restrict__ Bp,
                                              float* __restrict__ corr) {
  __shared__ float th_s[NC];
  __shared__ float red[256];
  int i = blockIdx.x;
  int tid = threadIdx.x;
  const float* tr = theta + (size_t)i * NC;
  const float* ar = aging + (size_t)i * NC;
  float psum = 0.f;
  for (int k = tid; k < NC; k += 256) {
    float th = tr[k] * ar[k];
    if (fabsf(th) < 0.01f) th = 0.f;              // straight-through forward
    th_s[k] = th;
    psum += fabsf(th);
  }
  red[tid] = psum;
  __syncthreads();
  for (int s = 128; s > 0; s >>= 1) {
    if (tid < s) red[tid] += red[tid + s];
    __syncthreads();
  }
  float inv_sum = 1.0f / red[0];
  unsigned short* out = Bp + (size_t)i * K_DIM;
  for (int k = tid; k < K_IN; k += 256) {
    float th = th_s[k];
    float w = fabsf(th) * inv_sum;
    out[k]        = f2bf((th >= 0.f) ? w : 0.f);  // Wp
    out[K_IN + k] = f2bf((th <  0.f) ? w : 0.f);  // Wn
  }
  if (tid == 0) {
    // constant-column contribution, kept in f32 (removes dominant bf16 error)
    float th1 = th_s[K_IN];       // pairs with a_aug ones column
    float th2 = th_s[K_IN + 1];   // pairs with a_aug zeros column
    float w1 = fabsf(th1) * inv_sum;
    float w2 = fabsf(th2) * inv_sum;
    float inv1 = 0.104f - 0.899f * fast_tanh((1.0f + 0.056f) * 3.858f);
    float inv0 = 0.104f - 0.899f * fast_tanh((0.0f + 0.056f) * 3.858f);
    float c = (th1 >= 0.f) ? w1 : w1 * inv1;      // a=1 on positive side
    c += (th2 >= 0.f) ? 0.0f : w2 * inv0;         // a=0 on positive side
    corr[i] = c;
  }
}

// ---------------------------------------------------------------------------
// gemm_fused: z = A' B'^T + corr[n]; out = 1.096 - 1.924/(1+e^{2(z-0.183)*24.1})
// m97 structure: 128x128 tile, BK=64, 4 waves (2x2), 16x16x32 bf16 MFMA,
// global_load_lds width=16 staging, 2-barrier K-loop.
// ---------------------------------------------------------------------------
__global__ __launch_bounds__(256) void gemm_fused(const unsigned short* __restrict__ A,
                                                  const unsigned short* __restrict__ B,
                                                  const float* __restrict__ corr,
                                                  float* __restrict__ C) {
  __shared__ unsigned short As[BM * BK];   // 16 KB
  __shared__ unsigned short Bs[BN * BK];   // 16 KB
  int tid = threadIdx.x;
  int bm0 = blockIdx.y * BM;
  int bn0 = blockIdx.x * BN;
  int w = tid >> 6, lane = tid & 63;
  int wm = (w >> 1) * 64, wn = (w & 1) * 64;   // wave 2x2 -> 64x64 out each
  int fr = lane & 15;                          // fragment row/col index
  int fk = (lane >> 4) * 8;                    // fragment k offset

  f32x4 acc[4][4] = {};

  // staging coords: 256 thr x 16B = 4 KB = 32 rows x 128B per issue
  int sr = tid >> 3;            // 0..31
  int sc = (tid & 7) * 8;       // bf16 col, 16B aligned
  const unsigned short* Ag = A + (size_t)(bm0 + sr) * K_DIM + sc;
  const unsigned short* Bg = B + (size_t)(bn0 + sr) * K_DIM + sc;
  char* AsB = (char*)As;
  char* BsB = (char*)Bs;

  for (int kt = 0; kt < K_DIM; kt += BK) {
#pragma unroll
    for (int is = 0; is < 4; ++is) {
      __builtin_amdgcn_global_load_lds(
          (const __attribute__((address_space(1))) unsigned int*)(Ag + kt + (size_t)is * 32 * K_DIM),
          (__attribute__((address_space(3))) unsigned int*)(AsB + is * 4096 + tid * 16),
          16, 0, 0);
    }
#pragma unroll
    for (int is = 0; is < 4; ++is) {
      __builtin_amdgcn_global_load_lds(
          (const __attribute__((address_space(1))) unsigned int*)(Bg + kt + (size_t)is * 32 * K_DIM),
          (__attribute__((address_space(3))) unsigned int*)(BsB + is * 4096 + tid * 16),
          16, 0, 0);
    }
    __syncthreads();   // compiler drains vmcnt before barrier
#pragma unroll
    for (int kk = 0; kk < 2; ++kk) {
      short8_t af[4], bf[4];
#pragma unroll
      for (int f = 0; f < 4; ++f)
        af[f] = *(const short8_t*)&As[(wm + f * 16 + fr) * BK + kk * 32 + fk];
#pragma unroll
      for (int f = 0; f < 4; ++f)
        bf[f] = *(const short8_t*)&Bs[(wn + f * 16 + fr) * BK + kk * 32 + fk];
#pragma unroll
      for (int fm = 0; fm < 4; ++fm)
#pragma unroll
        for (int fn = 0; fn < 4; ++fn)
          acc[fm][fn] = __builtin_amdgcn_mfma_f32_16x16x32_bf16(af[fm], bf[fn], acc[fm][fn], 0, 0, 0);
    }
    __syncthreads();
  }

  // epilogue: C/D layout col=lane&15, row=(lane>>4)*4+reg  [m89-verified]
  int rb = (lane >> 4) * 4;
#pragma unroll
  for (int fm = 0; fm < 4; ++fm) {
#pragma unroll
    for (int fn = 0; fn < 4; ++fn) {
      int n = bn0 + wn + fn * 16 + fr;
      float cr = corr[n];
      int mb = bm0 + wm + fm * 16 + rb;
#pragma unroll
      for (int j = 0; j < 4; ++j) {
        float z = acc[fm][fn][j] + cr;
        float e = __expf(2.0f * (z - 0.183f) * 24.1f);
        float outv = 1.096f - 1.924f * __builtin_amdgcn_rcpf(1.0f + e);
        C[(size_t)(mb + j) * N_DIM + n] = outv;
      }
    }
  }
}

// ---------------------------------------------------------------------------
extern "C" void kernel_launch(void* const* d_in, const int* in_sizes, int n_in,
                              void* d_out, int out_size, void* d_ws, size_t ws_size,
                              hipStream_t stream) {
  (void)in_sizes; (void)n_in; (void)out_size; (void)ws_size;
  const float* a_prev = (const float*)d_in[0];
  const float* theta  = (const float*)d_in[1];
  const float* aging  = (const float*)d_in[2];
  float* out = (float*)d_out;

  char* ws = (char*)d_ws;
  unsigned short* Ap = (unsigned short*)ws;                                  // 134.2 MB
  unsigned short* Bp = (unsigned short*)(ws + (size_t)M_DIM * K_DIM * 2);    //  67.1 MB
  float* corr = (float*)(ws + (size_t)M_DIM * K_DIM * 2 + (size_t)N_DIM * K_DIM * 2);  // 16 KB

  prep_A<<<(M_DIM * K_IN / 4) / 256, 256, 0, stream>>>(a_prev, Ap);
  prep_B<<<N_DIM, 256, 0, stream>>>(theta, aging, Bp, corr);
  dim3 grid(N_DIM / BN, M_DIM / BM);
  gemm_fused<<<grid, dim3(256), 0, stream>>>(Ap, Bp, corr, out);
}

// Round 2
// 497.088 us; speedup vs baseline: 1.6788x; 1.6788x over previous
//
#include <hip/hip_runtime.h>
#include <hip/hip_bf16.h>
#include <stdint.h>

// Problem dims (fixed by the reference setup_inputs):
//   a_previous [8192, 4096] f32, theta [4096, 4098] f32, aging [4096, 4098] f32
//   out [8192, 4096] f32
#define M_DIM 8192
#define N_DIM 4096
#define K_IN  4096          // n_in
#define NC    (K_IN + 2)    // 4098 theta/aging columns
#define K_DIM (2 * K_IN)    // GEMM K: [a | inv(a)] concatenated

#define BM 256
#define BN 256
#define BK 64
#define NT (K_DIM / BK)     // 128 K-tiles

typedef __attribute__((ext_vector_type(8))) short short8_t;   // 8 bf16 (4 VGPRs)
typedef __attribute__((ext_vector_type(4))) float f32x4;      // MFMA acc

__device__ __forceinline__ unsigned short f2bf(float f) {
  union { float f; unsigned u; } v; v.f = f;
  unsigned u = v.u;
  return (unsigned short)((u + 0x7FFFu + ((u >> 16) & 1u)) >> 16);
}

__device__ __forceinline__ float fast_tanh(float y) {
  float e = __expf(2.0f * y);
  return 1.0f - 2.0f * __builtin_amdgcn_rcpf(1.0f + e);
}

// ---------------------------------------------------------------------------
// prep_A: A' = [bf16(a) | bf16(inv(a))], shape [8192][8192] bf16
// ---------------------------------------------------------------------------
__global__ __launch_bounds__(256) void prep_A(const float* __restrict__ a,
                                              unsigned short* __restrict__ Ap) {
  int idx = blockIdx.x * 256 + threadIdx.x;
  int j  = idx >> 10;
  int k4 = (idx & 1023) << 2;
  float4 v = reinterpret_cast<const float4*>(a)[idx];
  float xs[4] = {v.x, v.y, v.z, v.w};
  ushort4 lv, rv;
  unsigned short l[4], r[4];
#pragma unroll
  for (int t = 0; t < 4; ++t) {
    float x = xs[t];
    l[t] = f2bf(x);
    float tnh = fast_tanh((x + 0.056f) * 3.858f);
    r[t] = f2bf(0.104f - 0.899f * tnh);
  }
  lv.x = l[0]; lv.y = l[1]; lv.z = l[2]; lv.w = l[3];
  rv.x = r[0]; rv.y = r[1]; rv.z = r[2]; rv.w = r[3];
  size_t base = (size_t)j * K_DIM + k4;
  *reinterpret_cast<ushort4*>(Ap + base)        = lv;
  *reinterpret_cast<ushort4*>(Ap + base + K_IN) = rv;
}

// ---------------------------------------------------------------------------
// prep_B: th = st(theta*aging); W = |th|/rowsum; B' = [Wp | Wn] bf16; corr f32
// ---------------------------------------------------------------------------
__global__ __launch_bounds__(256) void prep_B(const float* __restrict__ theta,
                                              const float* __restrict__ aging,
                                              unsigned short* __restrict__ Bp,
                                              float* __restrict__ corr) {
  __shared__ float th_s[NC];
  __shared__ float red[256];
  int i = blockIdx.x;
  int tid = threadIdx.x;
  const float* tr = theta + (size_t)i * NC;
  const float* ar = aging + (size_t)i * NC;
  float psum = 0.f;
  for (int k = tid; k < NC; k += 256) {
    float th = tr[k] * ar[k];
    if (fabsf(th) < 0.01f) th = 0.f;
    th_s[k] = th;
    psum += fabsf(th);
  }
  red[tid] = psum;
  __syncthreads();
  for (int s = 128; s > 0; s >>= 1) {
    if (tid < s) red[tid] += red[tid + s];
    __syncthreads();
  }
  float inv_sum = 1.0f / red[0];
  unsigned short* out = Bp + (size_t)i * K_DIM;
  for (int k = tid; k < K_IN; k += 256) {
    float th = th_s[k];
    float w = fabsf(th) * inv_sum;
    out[k]        = f2bf((th >= 0.f) ? w : 0.f);
    out[K_IN + k] = f2bf((th <  0.f) ? w : 0.f);
  }
  if (tid == 0) {
    float th1 = th_s[K_IN];
    float th2 = th_s[K_IN + 1];
    float w1 = fabsf(th1) * inv_sum;
    float w2 = fabsf(th2) * inv_sum;
    float inv1 = 0.104f - 0.899f * fast_tanh((1.0f + 0.056f) * 3.858f);
    float inv0 = 0.104f - 0.899f * fast_tanh((0.0f + 0.056f) * 3.858f);
    float c = (th1 >= 0.f) ? w1 : w1 * inv1;
    c += (th2 >= 0.f) ? 0.0f : w2 * inv0;
    corr[i] = c;
  }
}

// ---------------------------------------------------------------------------
// gemm_fused: 256x256 tile, BK=64, 8 waves (2Mx4N), 8-phase/2-K-tile schedule
// (T1 XCD swizzle + T2 XOR swizzle + T3/T4 counted vmcnt + T5 setprio).
// LDS: 2 buf x (A 32KB + B 32KB) = 128 KiB, dynamic.
// Swizzle (both sides): elem col ^= ((row&7)<<3); glds writes linear, the
// per-lane GLOBAL source is pre-swizzled (rule 21 involution pair).
// Half-tile stage schedule (window W = one K-tile, phases p0..p3):
//   p0: stage A-half0(W+1)   p1: stage A-half1(W+1)
//   p2: stage B-half0(W+2)   p3: stage B-half1(W+2), vmcnt(4)
// Region ledger: A halves of buf b are last read at window(b) p2; staged at
// next window's p0/p1. B halves last read at p1; staged at p2/p3. All writes
// land before first read via vmcnt(4) at each p3 (+ trailing barrier).
// ---------------------------------------------------------------------------
__global__ __launch_bounds__(512, 2) void gemm_fused(const unsigned short* __restrict__ A,
                                                     const unsigned short* __restrict__ B,
                                                     const float* __restrict__ corr,
                                                     float* __restrict__ C) {
  extern __shared__ unsigned short lds[];   // 65536 elems = 128 KiB
  const int tid  = threadIdx.x;
  const int lane = tid & 63;
  const int wid  = tid >> 6;     // 0..7
  const int wr   = wid >> 2;     // 0..1  -> M offset wr*128
  const int wc   = wid & 3;      // 0..3  -> N offset wc*64
  const int fr   = lane & 15;
  const int fk8  = (lane >> 4) * 8;

  // T1: XCD-aware swizzle; nwg = 512, divisible by 8 -> bijective
  const int bid = (int)blockIdx.x;
  const int sw  = (bid & 7) * 64 + (bid >> 3);
  const int bm0 = (sw >> 4) * BM;     // 32 M-blocks
  const int bn0 = (sw & 15) * BN;     // 16 N-blocks

  // ---- staging constants (per-thread). Linear LDS dest elem = t*8 within
  // issue; row_lin = t>>3, col_lin = (t&7)*8; source col pre-swizzled.
  const int colsw = ((tid & 7) * 8) ^ (((tid >> 3) & 7) << 3);
  const unsigned short* gA = A + (size_t)(bm0 + (tid >> 3)) * K_DIM + colsw;
  const unsigned short* gB = B + (size_t)(bn0 + (tid >> 3)) * K_DIM + colsw;
  char* ldsb = (char*)lds;
  const int dst_t = tid * 16;

  // ---- read-side swizzled fragment offsets
  const int flip = (fr & 7) << 3;          // row&7 == fr&7 for all frag rows
  const int cs0  = fk8 ^ flip;             // kk=0: col = 0*32 + fk8
  const int cs1  = (32 + fk8) ^ flip;      // kk=1
  const int aRow = (wr * 128 + fr) * 64;   // elem offset of frag base row
  const int bRow = (wc * 64 + fr) * 64;

  f32x4 acc[8][4] = {};

  // stage half-tile H (0/1) of matrix (ISA=1 -> A) for K-tile T: 2 x glds x16B
#define STAGE(ISA, H, T) do {                                                        \
    const unsigned short* _g = (ISA) ? gA : gB;                                      \
    const size_t _go = (size_t)((H) * 128) * K_DIM + (size_t)(T) * BK;               \
    char* _l = ldsb + (((T) & 1) * 65536) + ((ISA) ? 0 : 32768) + (H) * 16384 + dst_t; \
    __builtin_amdgcn_global_load_lds(                                                \
        (const __attribute__((address_space(1))) unsigned int*)(_g + _go),           \
        (__attribute__((address_space(3))) unsigned int*)_l, 16, 0, 0);              \
    __builtin_amdgcn_global_load_lds(                                                \
        (const __attribute__((address_space(1))) unsigned int*)(_g + _go + (size_t)64 * K_DIM), \
        (__attribute__((address_space(3))) unsigned int*)(_l + 8192), 16, 0, 0);     \
  } while (0)

#define MFMA(a, b, c) __builtin_amdgcn_mfma_f32_16x16x32_bf16((a), (b), (c), 0, 0, 0)

  // ---- prologue: tile0 fully + B halves of tile1 (12 loads); wait tile0 (8)
  STAGE(0, 0, 0); STAGE(0, 1, 0); STAGE(1, 0, 0); STAGE(1, 1, 0);
  STAGE(0, 0, 1); STAGE(0, 1, 1);
  asm volatile("s_waitcnt vmcnt(4)" ::: "memory");
  __builtin_amdgcn_s_barrier();
  asm volatile("" ::: "memory");

#pragma unroll 2
  for (int W = 0; W < NT; ++W) {
    const unsigned short* pa = lds + (W & 1) * 32768 + aRow;
    const unsigned short* pb = lds + (W & 1) * 32768 + 16384 + bRow;
    short8_t af[4][2], bf[4][2];

    // ===== phase 0: read A m0-3 (8) + B n0-1 (4); stage A0(W+1); MFMA 16
#pragma unroll
    for (int m = 0; m < 4; ++m) {
      af[m][0] = *(const short8_t*)(pa + m * 1024 + cs0);
      af[m][1] = *(const short8_t*)(pa + m * 1024 + cs1);
    }
#pragma unroll
    for (int n = 0; n < 2; ++n) {
      bf[n][0] = *(const short8_t*)(pb + n * 1024 + cs0);
      bf[n][1] = *(const short8_t*)(pb + n * 1024 + cs1);
    }
    if (W + 1 < NT) STAGE(1, 0, W + 1);
    __builtin_amdgcn_s_barrier();
    asm volatile("s_waitcnt lgkmcnt(0)" ::: "memory");
    __builtin_amdgcn_sched_barrier(0);
    __builtin_amdgcn_s_setprio(1);
#pragma unroll
    for (int m = 0; m < 4; ++m)
#pragma unroll
      for (int n = 0; n < 2; ++n) {
        acc[m][n] = MFMA(af[m][0], bf[n][0], acc[m][n]);
        acc[m][n] = MFMA(af[m][1], bf[n][1], acc[m][n]);
      }
    __builtin_amdgcn_s_setprio(0);
    __builtin_amdgcn_s_barrier();
    asm volatile("" ::: "memory");

    // ===== phase 1: read B n2-3 (4); stage A1(W+1); MFMA 16
#pragma unroll
    for (int n = 2; n < 4; ++n) {
      bf[n][0] = *(const short8_t*)(pb + n * 1024 + cs0);
      bf[n][1] = *(const short8_t*)(pb + n * 1024 + cs1);
    }
    if (W + 1 < NT) STAGE(1, 1, W + 1);
    __builtin_amdgcn_s_barrier();
    asm volatile("s_waitcnt lgkmcnt(0)" ::: "memory");
    __builtin_amdgcn_sched_barrier(0);
    __builtin_amdgcn_s_setprio(1);
#pragma unroll
    for (int m = 0; m < 4; ++m)
#pragma unroll
      for (int n = 2; n < 4; ++n) {
        acc[m][n] = MFMA(af[m][0], bf[n][0], acc[m][n]);
        acc[m][n] = MFMA(af[m][1], bf[n][1], acc[m][n]);
      }
    __builtin_amdgcn_s_setprio(0);
    __builtin_amdgcn_s_barrier();
    asm volatile("" ::: "memory");

    // ===== phase 2: read A m4-7 (8); stage B0(W+2); MFMA 16
#pragma unroll
    for (int m = 0; m < 4; ++m) {
      af[m][0] = *(const short8_t*)(pa + (m + 4) * 1024 + cs0);
      af[m][1] = *(const short8_t*)(pa + (m + 4) * 1024 + cs1);
    }
    if (W + 2 < NT) STAGE(0, 0, W + 2);
    __builtin_amdgcn_s_barrier();
    asm volatile("s_waitcnt lgkmcnt(0)" ::: "memory");
    __builtin_amdgcn_sched_barrier(0);
    __builtin_amdgcn_s_setprio(1);
#pragma unroll
    for (int m = 0; m < 4; ++m)
#pragma unroll
      for (int n = 0; n < 2; ++n) {
        acc[m + 4][n] = MFMA(af[m][0], bf[n][0], acc[m + 4][n]);
        acc[m + 4][n] = MFMA(af[m][1], bf[n][1], acc[m + 4][n]);
      }
    __builtin_amdgcn_s_setprio(0);
    __builtin_amdgcn_s_barrier();
    asm volatile("" ::: "memory");

    // ===== phase 3: no reads; stage B1(W+2); MFMA 16; counted vmcnt
    if (W + 2 < NT) STAGE(0, 1, W + 2);
    __builtin_amdgcn_s_barrier();
    __builtin_amdgcn_sched_barrier(0);
    __builtin_amdgcn_s_setprio(1);
#pragma unroll
    for (int m = 0; m < 4; ++m)
#pragma unroll
      for (int n = 2; n < 4; ++n) {
        acc[m + 4][n] = MFMA(af[m][0], bf[n][0], acc[m + 4][n]);
        acc[m + 4][n] = MFMA(af[m][1], bf[n][1], acc[m + 4][n]);
      }
    __builtin_amdgcn_s_setprio(0);
    if (W < NT - 2) { asm volatile("s_waitcnt vmcnt(4)" ::: "memory"); }
    else            { asm volatile("s_waitcnt vmcnt(0)" ::: "memory"); }
    __builtin_amdgcn_s_barrier();
    asm volatile("" ::: "memory");
  }

  // ---- epilogue: z + corr, activation, store
  const int rb = (lane >> 4) * 4;
#pragma unroll
  for (int n = 0; n < 4; ++n) {
    const int col = bn0 + wc * 64 + n * 16 + fr;
    const float cr = corr[col];
#pragma unroll
    for (int mi = 0; mi < 8; ++mi) {
      const int row0 = bm0 + wr * 128 + mi * 16 + rb;
#pragma unroll
      for (int j = 0; j < 4; ++j) {
        float z = acc[mi][n][j] + cr;
        float e = __expf((z - 0.183f) * 48.2f);
        C[(size_t)(row0 + j) * N_DIM + col] = 1.096f - 1.924f * __builtin_amdgcn_rcpf(1.0f + e);
      }
    }
  }
#undef STAGE
#undef MFMA
}

// ---------------------------------------------------------------------------
extern "C" void kernel_launch(void* const* d_in, const int* in_sizes, int n_in,
                              void* d_out, int out_size, void* d_ws, size_t ws_size,
                              hipStream_t stream) {
  (void)in_sizes; (void)n_in; (void)out_size; (void)ws_size;
  const float* a_prev = (const float*)d_in[0];
  const float* theta  = (const float*)d_in[1];
  const float* aging  = (const float*)d_in[2];
  float* out = (float*)d_out;

  char* ws = (char*)d_ws;
  unsigned short* Ap = (unsigned short*)ws;                                  // 134.2 MB
  unsigned short* Bp = (unsigned short*)(ws + (size_t)M_DIM * K_DIM * 2);    //  67.1 MB
  float* corr = (float*)(ws + (size_t)M_DIM * K_DIM * 2 + (size_t)N_DIM * K_DIM * 2);

  prep_A<<<(M_DIM * K_IN / 4) / 256, 256, 0, stream>>>(a_prev, Ap);
  prep_B<<<N_DIM, 256, 0, stream>>>(theta, aging, Bp, corr);

  // 128 KiB dynamic LDS (> 64 KiB default): set attribute each call (idempotent)
  (void)hipFuncSetAttribute((const void*)gemm_fused,
                            hipFuncAttributeMaxDynamicSharedMemorySize, 131072);
  gemm_fused<<<dim3((M_DIM / BM) * (N_DIM / BN)), dim3(512), 131072, stream>>>(Ap, Bp, corr, out);
}